// Round 7
// baseline (186.058 us; speedup 1.0000x reference)
//
#include <hip/hip_runtime.h>

#define HIMG 256
#define WIMG 256
#define CCH  32
#define JBOX 64
#define BIMG 8
#define HGT  8
#define CPW  8   // channels per wave: 256 threads = 4 waves x 8 channels

// Grid: (tiles, B*J). Block 256 = 4 waves; wave wv = channels [wv*8, wv*8+8),
// lane = output column within tile; each thread loops over ALL 8 h rows.
// R7: amortize per-wave setup + first-load latency across an 8x longer wave
// lifetime; x-taps/x-weights are h-invariant and computed once; the unrolled
// h-loop gives independent load batches the compiler can pipeline.
__global__ __launch_bounds__(256, 4) void roi_kernel(
    const float* __restrict__ img,     // (B, C, HIMG, WIMG)
    const float* __restrict__ boxes,   // (B, J, 5)
    float* __restrict__ res,           // (B, J, C, HGT, max_w)
    float* __restrict__ mask,          // (B, J, max_w)
    int max_w)
{
    const int tile = blockIdx.x;
    const int bj   = blockIdx.y;      // 0..511
    const int b    = bj >> 6;         // J = 64
    const int wv   = threadIdx.x >> 6;   // 0..3 channel group
    const int lane = threadIdx.x & 63;
    const int i    = tile * 64 + lane;

    const float left = boxes[bj * 5 + 0];
    const float top  = boxes[bj * 5 + 1];
    const float bw   = boxes[bj * 5 + 2] - left;
    const float bh   = boxes[bj * 5 + 3] - top;

    // width = int32(bw/bh * 8) with f32 ops + truncation (matches numpy).
    const int   width  = (int)(bw / bh * 8.0f);
    const float each_w = bw / ((float)width - 1.0f);
    const float each_h = bh / 7.0f;

    if (i >= max_w) return;
    const bool in_w = (i < width);

    if (wv == 0) {
        mask[(size_t)bj * max_w + i] = in_w ? 1.0f : 0.0f;
    }

    // res[((bj*C + c)*HGT + h)*max_w + i]; this thread's h=0, first channel.
    float* resp = res + (((size_t)bj * CCH + wv * CPW) * HGT) * (size_t)max_w + i;
    const size_t c_stride = (size_t)HGT * max_w;   // channel stride
    const size_t h_stride = (size_t)max_w;         // h stride

    if (!in_w) {
        // Masked region: 64 zero stores, no image reads.
        #pragma unroll
        for (int c = 0; c < CPW; ++c) {
            #pragma unroll
            for (int h = 0; h < HGT; ++h) {
                resp[(size_t)c * c_stride + (size_t)h * h_stride] = 0.0f;
            }
        }
        return;
    }

    // x taps/weights: h-invariant, computed ONCE per thread.
    // Separate mul/add roundings so floor() matches numpy bit-exactly.
    const float x  = __fadd_rn(__fmul_rn((float)i, each_w), left);
    const int   xf = (int)floorf(x);
    const int   x0 = min(max(xf,     0), WIMG - 1);
    const int   x1 = min(max(xf + 1, 0), WIMG - 1);
    const float wx1 = (float)x1 - x;
    const float wx0 = x - (float)x0;

    // Wave-uniform image base for this wave's 8 channels.
    const float* im = img + ((size_t)b * CCH + wv * CPW) * (HIMG * WIMG);

    #pragma unroll
    for (int h = 0; h < HGT; ++h) {
        const float y  = __fadd_rn(__fmul_rn((float)h, each_h), top);
        const int   yf = (int)floorf(y);
        const int   y0 = min(max(yf,     0), HIMG - 1);
        const int   y1 = min(max(yf + 1, 0), HIMG - 1);
        const float wy1 = (float)y1 - y;
        const float wy0 = y - (float)y0;

        const float wa = wx1 * wy1;
        const float wb = wx1 * wy0;
        const float wc = wx0 * wy1;
        const float wd = wx0 * wy0;

        const int o00 = y0 * WIMG + x0;
        const int o10 = y1 * WIMG + x0;
        const int o01 = y0 * WIMG + x1;
        const int o11 = y1 * WIMG + x1;

        #pragma unroll
        for (int c = 0; c < CPW; ++c) {
            const float* imc = im + (size_t)c * (HIMG * WIMG);
            const float va = imc[o00];
            const float vb = imc[o10];
            const float vc = imc[o01];
            const float vd = imc[o11];
            const float val = va * wa + vb * wb + vc * wc + vd * wd;
            resp[(size_t)c * c_stride + (size_t)h * h_stride] = val;
        }
    }
}

extern "C" void kernel_launch(void* const* d_in, const int* in_sizes, int n_in,
                              void* d_out, int out_size, void* d_ws, size_t ws_size,
                              hipStream_t stream) {
    const float* img   = (const float*)d_in[0];
    const float* boxes = (const float*)d_in[1];
    float* out = (float*)d_out;

    const int per_w = BIMG * JBOX * CCH * HGT + BIMG * JBOX;  // 131584
    const int max_w = out_size / per_w;

    float* res  = out;
    float* mask = out + (size_t)BIMG * JBOX * CCH * HGT * max_w;

    const int tiles = (max_w + 63) / 64;                // 3 for max_w=169
    dim3 grid(tiles, BIMG * JBOX);                      // (3, 512)
    roi_kernel<<<grid, 256, 0, stream>>>(img, boxes, res, mask, max_w);
}

// Round 8
// 155.259 us; speedup vs baseline: 1.1984x; 1.1984x over previous
//
#include <hip/hip_runtime.h>

#define HIMG 256
#define WIMG 256
#define CCH  32
#define JBOX 64
#define BIMG 8
#define HGT  8
#define CPW  8   // channels per wave: 256 threads = 4 waves x 8 channels
#define NXCD 8
#define TILES_MAX 3   // ceil(max_w/64); max_w=169 -> 3 (asserted on host side)

// R8: R5/R6 structure + XCD-locality swizzle.
// 1D grid of 12288 blocks. Dispatch order d -> XCD d%8 (rr heuristic).
// Remap so all 24 blocks (3 tiles x 8 h) of one box bj share d%8 (one XCD)
// and are consecutive in seq -> the box's ~50-100KB row footprint stays
// L2-resident instead of being refetched from L3 by all 8 XCDs.
__global__ __launch_bounds__(256, 4) void roi_kernel(
    const float* __restrict__ img,     // (B, C, HIMG, WIMG)
    const float* __restrict__ boxes,   // (B, J, 5)
    float* __restrict__ res,           // (B, J, C, HGT, max_w)
    float* __restrict__ mask,          // (B, J, max_w)
    int max_w, int tiles)
{
    // ---- swizzle: d = blockIdx.x in dispatch order ----
    const int d    = blockIdx.x;
    const int slot = d & (NXCD - 1);        // XCD id under rr dispatch
    const int seq  = d >> 3;                // 0 .. 512*tiles*8/8 - 1
    const int per_box = tiles * HGT;        // 24 blocks per box
    const int boxes_per_slot = (BIMG * JBOX) / NXCD;   // 64
    const int bj   = slot * boxes_per_slot + seq / per_box;
    const int wi   = seq % per_box;
    const int tile = wi >> 3;               // 0..tiles-1
    const int h    = wi & 7;

    const int b    = bj >> 6;               // J = 64
    const int wv   = threadIdx.x >> 6;      // 0..3 channel group
    const int lane = threadIdx.x & 63;
    const int i    = tile * 64 + lane;

    const float left = boxes[bj * 5 + 0];
    const float top  = boxes[bj * 5 + 1];
    const float bw   = boxes[bj * 5 + 2] - left;
    const float bh   = boxes[bj * 5 + 3] - top;

    // width = int32(bw/bh * 8) with f32 ops + truncation (matches numpy).
    const int   width  = (int)(bw / bh * 8.0f);
    const float each_w = bw / ((float)width - 1.0f);
    const float each_h = bh / 7.0f;

    if (i >= max_w) return;
    const bool in_w = (i < width);

    if (h == 0 && wv == 0) {
        mask[(size_t)bj * max_w + i] = in_w ? 1.0f : 0.0f;
    }

    // res[((bj*C + c)*HGT + h)*max_w + i], this wave's first channel.
    float* resp = res + (((size_t)bj * CCH + wv * CPW) * HGT + h) * (size_t)max_w + i;
    const size_t c_stride = (size_t)HGT * max_w;

    if (!in_w) {
        #pragma unroll
        for (int c = 0; c < CPW; ++c) {
            resp[(size_t)c * c_stride] = 0.0f;
        }
        return;
    }

    // Separate mul/add roundings so floor() matches numpy bit-exactly.
    const float x = __fadd_rn(__fmul_rn((float)i, each_w), left);
    const float y = __fadd_rn(__fmul_rn((float)h, each_h), top);

    const int xf = (int)floorf(x);
    const int yf = (int)floorf(y);
    const int x0 = min(max(xf,     0), WIMG - 1);
    const int x1 = min(max(xf + 1, 0), WIMG - 1);
    const int y0 = min(max(yf,     0), HIMG - 1);
    const int y1 = min(max(yf + 1, 0), HIMG - 1);

    const float wx1 = (float)x1 - x;
    const float wx0 = x - (float)x0;
    const float wy1 = (float)y1 - y;
    const float wy0 = y - (float)y0;

    const float wa = wx1 * wy1;
    const float wb = wx1 * wy0;
    const float wc = wx0 * wy1;
    const float wd = wx0 * wy0;

    const float* im = img + ((size_t)b * CCH + wv * CPW) * (HIMG * WIMG);
    const int o00 = y0 * WIMG + x0;
    const int o10 = y1 * WIMG + x0;
    const int o01 = y0 * WIMG + x1;
    const int o11 = y1 * WIMG + x1;

    // Issue all 32 loads, then blend (kept from R6; neutral but harmless).
    float va[CPW], vb[CPW], vc[CPW], vd[CPW];
    #pragma unroll
    for (int c = 0; c < CPW; ++c) {
        const float* imc = im + (size_t)c * (HIMG * WIMG);
        va[c] = imc[o00];
        vb[c] = imc[o10];
        vc[c] = imc[o01];
        vd[c] = imc[o11];
    }
    #pragma unroll
    for (int c = 0; c < CPW; ++c) {
        const float val = va[c] * wa + vb[c] * wb + vc[c] * wc + vd[c] * wd;
        resp[(size_t)c * c_stride] = val;
    }
}

extern "C" void kernel_launch(void* const* d_in, const int* in_sizes, int n_in,
                              void* d_out, int out_size, void* d_ws, size_t ws_size,
                              hipStream_t stream) {
    const float* img   = (const float*)d_in[0];
    const float* boxes = (const float*)d_in[1];
    float* out = (float*)d_out;

    const int per_w = BIMG * JBOX * CCH * HGT + BIMG * JBOX;  // 131584
    const int max_w = out_size / per_w;

    float* res  = out;
    float* mask = out + (size_t)BIMG * JBOX * CCH * HGT * max_w;

    const int tiles  = (max_w + 63) / 64;               // 3 for max_w=169
    const int blocks = BIMG * JBOX * tiles * HGT;       // 12288
    roi_kernel<<<blocks, 256, 0, stream>>>(img, boxes, res, mask, max_w, tiles);
}

// Round 9
// 154.286 us; speedup vs baseline: 1.2059x; 1.0063x over previous
//
#include <hip/hip_runtime.h>

#define HIMG 256
#define WIMG 256
#define CCH  32
#define JBOX 64
#define BIMG 8
#define HGT  8
#define CPB  8     // channels per block
#define NCG  (CCH / CPB)   // 4 channel-groups
#define NXCD 8
#define LSEG 204   // staged cols: xs=floor(left)<=40, span<=204, xs+203<=243<256

// R9: kill divergent gathers. Block = (bj, h, ch-group). Stage 8 ch x 2 rows
// x 204 contiguous cols into LDS with fully coalesced loads (2 lines/instr in
// TA vs ~6-8 for divergent gathers), then take bilinear taps from LDS.
// 26 KB LDS -> 6 blocks/CU (R4 died at 52 KB -> 2 blocks/CU).
// XCD swizzle keeps each box's rows L2-local across its 32 blocks.
__global__ __launch_bounds__(256, 6) void roi_kernel(
    const float* __restrict__ img,     // (B, C, HIMG, WIMG)
    const float* __restrict__ boxes,   // (B, J, 5)
    float* __restrict__ res,           // (B, J, C, HGT, max_w)
    float* __restrict__ mask,          // (B, J, max_w)
    int max_w)
{
    __shared__ float smem[CPB][2][LSEG];   // 26,112 B

    // Swizzle: 32 blocks (8 h x 4 cg) of one box share d%8 -> one XCD.
    const int d    = blockIdx.x;
    const int slot = d & (NXCD - 1);
    const int seq  = d >> 3;               // 0..2047
    const int bj   = slot * ((BIMG * JBOX) / NXCD) + (seq >> 5);
    const int rem  = seq & 31;
    const int h    = rem >> 2;             // 0..7
    const int cg   = rem & 3;              // 0..3
    const int b    = bj >> 6;              // J = 64
    const int tid  = threadIdx.x;

    const float left = boxes[bj * 5 + 0];
    const float top  = boxes[bj * 5 + 1];
    const float bw   = boxes[bj * 5 + 2] - left;
    const float bh   = boxes[bj * 5 + 3] - top;

    // width = int32(bw/bh * 8) with f32 ops + truncation (matches numpy).
    const int   width  = (int)(bw / bh * 8.0f);
    const float each_w = bw / ((float)width - 1.0f);
    const float each_h = bh / 7.0f;

    // y taps (block-uniform). Separate mul/add roundings (match numpy).
    const float y  = __fadd_rn(__fmul_rn((float)h, each_h), top);
    const int   yf = (int)floorf(y);
    const int   y0 = min(max(yf,     0), HIMG - 1);
    const int   y1 = min(max(yf + 1, 0), HIMG - 1);
    const float wy1 = (float)y1 - y;
    const float wy0 = y - (float)y0;

    const int xs = max((int)floorf(left), 0);   // <= 40

    // ---- coalesced staging: 16 (ch,row) segments x 204 cols ----
    {
        const float* base = img + ((size_t)b * CCH + cg * CPB) * (HIMG * WIMG);
        if (tid < LSEG) {
            #pragma unroll
            for (int seg = 0; seg < 2 * CPB; ++seg) {
                const int ch  = seg >> 1;
                const int row = (seg & 1) ? y1 : y0;
                smem[ch][seg & 1][tid] =
                    base[((size_t)ch * HIMG + row) * WIMG + xs + tid];
            }
        }
    }

    __syncthreads();

    const int  i    = tid;
    const bool have = (i < max_w);
    const bool in_w = (i < width);

    if (h == 0 && cg == 0 && have) {
        mask[(size_t)bj * max_w + i] = in_w ? 1.0f : 0.0f;
    }

    // res[((bj*C + c)*HGT + h)*max_w + i], this block's first channel.
    float* resp = res + (((size_t)bj * CCH + cg * CPB) * HGT + h) * (size_t)max_w + i;
    const size_t c_stride = (size_t)HGT * max_w;

    if (!have) return;

    if (!in_w) {
        #pragma unroll
        for (int c = 0; c < CPB; ++c) {
            resp[(size_t)c * c_stride] = 0.0f;
        }
        return;
    }

    // x taps (per thread). Separate roundings to match numpy floor exactly.
    const float x  = __fadd_rn(__fmul_rn((float)i, each_w), left);
    const int   xf = (int)floorf(x);
    const int   x0 = min(max(xf,     0), WIMG - 1);
    const int   x1 = min(max(xf + 1, 0), WIMG - 1);
    const float wx1 = (float)x1 - x;
    const float wx0 = x - (float)x0;

    const float wa = wx1 * wy1;
    const float wb = wx1 * wy0;
    const float wc = wx0 * wy1;
    const float wd = wx0 * wy0;

    // LDS columns: guaranteed 0 <= lx0 <= lx1 <= 203 (span <= 204, see top).
    const int lx0 = x0 - xs;
    const int lx1 = x1 - xs;

    #pragma unroll
    for (int c = 0; c < CPB; ++c) {
        const float va = smem[c][0][lx0];
        const float vc = smem[c][0][lx1];
        const float vb = smem[c][1][lx0];
        const float vd = smem[c][1][lx1];
        const float val = va * wa + vb * wb + vc * wc + vd * wd;
        resp[(size_t)c * c_stride] = val;
    }
}

extern "C" void kernel_launch(void* const* d_in, const int* in_sizes, int n_in,
                              void* d_out, int out_size, void* d_ws, size_t ws_size,
                              hipStream_t stream) {
    const float* img   = (const float*)d_in[0];
    const float* boxes = (const float*)d_in[1];
    float* out = (float*)d_out;

    const int per_w = BIMG * JBOX * CCH * HGT + BIMG * JBOX;  // 131584
    const int max_w = out_size / per_w;

    float* res  = out;
    float* mask = out + (size_t)BIMG * JBOX * CCH * HGT * max_w;

    const int blocks = BIMG * JBOX * HGT * NCG;   // 16384
    roi_kernel<<<blocks, 256, 0, stream>>>(img, boxes, res, mask, max_w);
}

// Round 10
// 151.650 us; speedup vs baseline: 1.2269x; 1.0174x over previous
//
#include <hip/hip_runtime.h>

#define HIMG 256
#define WIMG 256
#define CCH  32
#define JBOX 64
#define BIMG 8
#define HGT  8
#define CPB  8     // channels per block
#define NCG  (CCH / CPB)
#define NXCD 8
#define LSEG 208   // staging cols from xs4=xs&~3: span<=207, xs4+207<=247<256

// R10: memory-pipe instruction reduction (model: CU LDS/TA issue-bound).
// - LDS layout float2[ch][col] = (row0,row1) pair: genuinely 8B-aligned ->
//   taps are ds_read_b64 (16/thread) instead of ds_read_b32 (32/thread).
// - Staging: float4 global loads at genuinely-16B-aligned xs4 (image rows are
//   1KB-aligned; NOT R3's unaligned UB) + float2 LDS writes.
// Grid/swizzle identical to R9 (32 blocks per box share one XCD).
__global__ __launch_bounds__(256, 6) void roi_kernel(
    const float* __restrict__ img,     // (B, C, HIMG, WIMG)
    const float* __restrict__ boxes,   // (B, J, 5)
    float* __restrict__ res,           // (B, J, C, HGT, max_w)
    float* __restrict__ mask,          // (B, J, max_w)
    int max_w)
{
    __shared__ float2 smem2[CPB][LSEG];   // 13,312 B

    const int d    = blockIdx.x;
    const int slot = d & (NXCD - 1);
    const int seq  = d >> 3;
    const int bj   = slot * ((BIMG * JBOX) / NXCD) + (seq >> 5);
    const int rem  = seq & 31;
    const int h    = rem >> 2;             // 0..7
    const int cg   = rem & 3;              // 0..3
    const int b    = bj >> 6;              // J = 64
    const int tid  = threadIdx.x;

    const float left = boxes[bj * 5 + 0];
    const float top  = boxes[bj * 5 + 1];
    const float bw   = boxes[bj * 5 + 2] - left;
    const float bh   = boxes[bj * 5 + 3] - top;

    // width = int32(bw/bh * 8) with f32 ops + truncation (matches numpy).
    const int   width  = (int)(bw / bh * 8.0f);
    const float each_w = bw / ((float)width - 1.0f);
    const float each_h = bh / 7.0f;

    // y taps (block-uniform). Separate mul/add roundings (match numpy).
    const float y  = __fadd_rn(__fmul_rn((float)h, each_h), top);
    const int   yf = (int)floorf(y);
    const int   y0 = min(max(yf,     0), HIMG - 1);
    const int   y1 = min(max(yf + 1, 0), HIMG - 1);
    const float wy1 = (float)y1 - y;
    const float wy0 = y - (float)y0;

    const int xs  = max((int)floorf(left), 0);   // <= 40
    const int xs4 = xs & ~3;                     // 16B-aligned window start

    // ---- staging: 2 iters x 256 threads cover 8 ch x 52 float4 slots ----
    {
        const float* base = img + ((size_t)b * CCH + cg * CPB) * (HIMG * WIMG);
        #pragma unroll
        for (int it = 0; it < 2; ++it) {
            const int item = it * 256 + tid;     // 0..511
            const int ch   = item >> 6;          // 0..7
            const int l    = item & 63;          // float4 slot
            if (l < 52) {                        // 52*4 = 208 cols
                const float* r0p = base + ((size_t)ch * HIMG + y0) * WIMG + xs4 + l * 4;
                const float* r1p = base + ((size_t)ch * HIMG + y1) * WIMG + xs4 + l * 4;
                const float4 q0 = *reinterpret_cast<const float4*>(r0p);  // 16B-aligned
                const float4 q1 = *reinterpret_cast<const float4*>(r1p);
                smem2[ch][l * 4 + 0] = make_float2(q0.x, q1.x);
                smem2[ch][l * 4 + 1] = make_float2(q0.y, q1.y);
                smem2[ch][l * 4 + 2] = make_float2(q0.z, q1.z);
                smem2[ch][l * 4 + 3] = make_float2(q0.w, q1.w);
            }
        }
    }

    __syncthreads();

    const int  i    = tid;
    const bool have = (i < max_w);
    const bool in_w = (i < width);

    if (h == 0 && cg == 0 && have) {
        mask[(size_t)bj * max_w + i] = in_w ? 1.0f : 0.0f;
    }

    float* resp = res + (((size_t)bj * CCH + cg * CPB) * HGT + h) * (size_t)max_w + i;
    const size_t c_stride = (size_t)HGT * max_w;

    if (!have) return;

    if (!in_w) {
        #pragma unroll
        for (int c = 0; c < CPB; ++c) {
            resp[(size_t)c * c_stride] = 0.0f;
        }
        return;
    }

    // x taps (per thread); separate roundings to match numpy floor exactly.
    const float x  = __fadd_rn(__fmul_rn((float)i, each_w), left);
    const int   xf = (int)floorf(x);
    const int   x0 = min(max(xf,     0), WIMG - 1);
    const int   x1 = min(max(xf + 1, 0), WIMG - 1);
    const float wx1 = (float)x1 - x;
    const float wx0 = x - (float)x0;

    const float wa = wx1 * wy1;   // (row0, x0)
    const float wb = wx1 * wy0;   // (row1, x0)
    const float wc = wx0 * wy1;   // (row0, x1)
    const float wd = wx0 * wy0;   // (row1, x1)

    // LDS columns within the staged window (always in-range for valid data).
    const int lx0 = min(max(x0 - xs4, 0), LSEG - 1);
    const int lx1 = min(max(x1 - xs4, 0), LSEG - 1);

    #pragma unroll
    for (int c = 0; c < CPB; ++c) {
        const float2 p0 = smem2[c][lx0];   // (row0[x0], row1[x0]) - ds_read_b64
        const float2 p1 = smem2[c][lx1];   // (row0[x1], row1[x1])
        const float val = p0.x * wa + p0.y * wb + p1.x * wc + p1.y * wd;
        resp[(size_t)c * c_stride] = val;
    }
}

extern "C" void kernel_launch(void* const* d_in, const int* in_sizes, int n_in,
                              void* d_out, int out_size, void* d_ws, size_t ws_size,
                              hipStream_t stream) {
    const float* img   = (const float*)d_in[0];
    const float* boxes = (const float*)d_in[1];
    float* out = (float*)d_out;

    const int per_w = BIMG * JBOX * CCH * HGT + BIMG * JBOX;  // 131584
    const int max_w = out_size / per_w;

    float* res  = out;
    float* mask = out + (size_t)BIMG * JBOX * CCH * HGT * max_w;

    const int blocks = BIMG * JBOX * HGT * NCG;   // 16384
    roi_kernel<<<blocks, 256, 0, stream>>>(img, boxes, res, mask, max_w);
}